// Round 7
// baseline (1152.233 us; speedup 1.0000x reference)
//
#include <hip/hip_runtime.h>
#include <hip/hip_cooperative_groups.h>
#include <math.h>

namespace cg = cooperative_groups;

#define B_ 2
#define C_ 32
#define D_ 32
#define H_ 32
#define W_ 64
#define HW_ (H_*W_)         // 2048
#define DHW_ (D_*H_*W_)     // 65536
#define CDHW_ (C_*DHW_)     // 2097152
#define NSP_ DHW_           // spatial points per batch
#define BN_N_ (B_*DHW_)     // 131072
#define ACC_OFF 16777216    // byte offset of reduction area in ws (after MT)
#define BORDER 1e-3

// ws: MT [b][p][c] 16MB (holds z2 = relu(M-x) after ring-D); at ACC_OFF:
//   thrp[2] double (fallback path only), npart[1024] double2 at +256,
//   spart: coop = float2[32*1024], fallback = double2[512], at +256+16384.
// Every slot written before read each call -> no zeroing (poison-safe).

__device__ __forceinline__ float dist32(const float* col, const float* nb) {
    float d0 = 0.f, d1 = 0.f, d2 = 0.f, d3 = 0.f;
#pragma unroll
    for (int c = 0; c < 32; c += 4) {
        d0 += fabsf(col[c+0] - nb[c+0]);
        d1 += fabsf(col[c+1] - nb[c+1]);
        d2 += fabsf(col[c+2] - nb[c+2]);
        d3 += fabsf(col[c+3] - nb[c+3]);
    }
    return (d0 + d1) + (d2 + d3);
}

__device__ __forceinline__ float dist16(const float* col, const float* nb) {
    float d0 = 0.f, d1 = 0.f, d2 = 0.f, d3 = 0.f;
#pragma unroll
    for (int c = 0; c < 16; c += 4) {
        d0 += fabsf(col[c+0] - nb[c+0]);
        d1 += fabsf(col[c+1] - nb[c+1]);
        d2 += fabsf(col[c+2] - nb[c+2]);
        d3 += fabsf(col[c+3] - nb[c+3]);
    }
    return (d0 + d1) + (d2 + d3);
}

__device__ __forceinline__ bool gate(float ds, double thr, const float* col, const float* nb) {
    bool border = fabs((double)ds - thr) < BORDER;
    if (__ballot(border)) {
        double d64 = 0.0;
#pragma unroll
        for (int c = 0; c < 32; ++c) d64 += fabs((double)col[c] - (double)nb[c]);
        return d64 < thr;
    }
    return (double)ds < thr;
}

// ======================= fused cooperative kernel =======================

// ring phase body (H or D axis), 256 threads, 8 rings (one parity) per block
template<int AS, bool Z2T>
__device__ __forceinline__ void ring_phase(const float* __restrict__ x, float* __restrict__ MT,
                                           const double* thrs, float* smem, int blk, int t) {
    constexpr int FS = (AS == W_) ? HW_ : W_;
    int par = blk & 1, wt = (blk >> 1) & 7, F = (blk >> 4) & 31, b = blk >> 9;
    int w0 = wt * 8;
    double thr = thrs[b];
    const float* xb = x + (size_t)b * CDHW_ + (size_t)F * FS + w0;
#pragma unroll
    for (int it = 0; it < 4; ++it) {
        int f = it * 256 + t;                        // 0..1023 float4s
        int c = f >> 5, rem = f & 31, j = rem >> 1, wq = rem & 1;
        float4 v = *(const float4*)(xb + (size_t)c * DHW_ + (size_t)(2 * j + par) * AS + wq * 4);
        int sl = (((c >> 2) ^ (j & 7)) << 2) + (c & 3);
        int rb = (wq * 4) * 512 + j * 32 + sl;
        smem[rb] = v.x; smem[rb + 512] = v.y; smem[rb + 1024] = v.z; smem[rb + 1536] = v.w;
    }
    __syncthreads();
    int wl = t & 7, half = (t >> 3) & 1, pos = t >> 4;   // 8 x 2 x 16
    const float* Lr = smem + wl * 512;
    int qb = half * 4;
    float col[16], Mv[16], nb[16];
#pragma unroll
    for (int k = 0; k < 4; ++k) {
        float4 cv = *(const float4*)(Lr + pos * 32 + (((qb + k) ^ (pos & 7)) << 2));
        col[4*k] = cv.x; col[4*k+1] = cv.y; col[4*k+2] = cv.z; col[4*k+3] = cv.w;
    }
#pragma unroll
    for (int c = 0; c < 16; ++c) Mv[c] = col[c];
    for (int s = 1; s < 16; ++s) {
        int jj = (pos - s) & 15;
#pragma unroll
        for (int k = 0; k < 4; ++k) {
            float4 nv = *(const float4*)(Lr + jj * 32 + (((qb + k) ^ (jj & 7)) << 2));
            nb[4*k] = nv.x; nb[4*k+1] = nv.y; nb[4*k+2] = nv.z; nb[4*k+3] = nv.w;
        }
        float dh = dist16(col, nb);
        float ds = dh + __shfl_xor(dh, 8, 64);
        bool cmp;
        bool border = fabs((double)ds - thr) < BORDER;
        if (__ballot(border)) {
            double d64h = 0.0;
#pragma unroll
            for (int c = 0; c < 16; ++c) d64h += fabs((double)col[c] - (double)nb[c]);
            double other = __shfl_xor(d64h, 8, 64);
            cmp = (d64h + other) < thr;
        } else {
            cmp = (double)ds < thr;
        }
#pragma unroll
        for (int c = 0; c < 16; ++c) Mv[c] = (cmp && nb[c] > Mv[c]) ? nb[c] : Mv[c];
    }
    size_t p = (size_t)F * FS + (size_t)(2 * pos + par) * AS + w0 + wl;
    float* mp = MT + ((size_t)b * 65536 + p) * 32 + half * 16;
#pragma unroll
    for (int k = 0; k < 4; ++k) {
        float4 old = *(const float4*)(mp + 4 * k);
        float m0 = fmaxf(old.x, Mv[4*k]);   float m1 = fmaxf(old.y, Mv[4*k+1]);
        float m2 = fmaxf(old.z, Mv[4*k+2]); float m3 = fmaxf(old.w, Mv[4*k+3]);
        float4 o;
        if (Z2T) {
            o.x = fmaxf(m0 - col[4*k],   0.f); o.y = fmaxf(m1 - col[4*k+1], 0.f);
            o.z = fmaxf(m2 - col[4*k+2], 0.f); o.w = fmaxf(m3 - col[4*k+3], 0.f);
        } else {
            o.x = m0; o.y = m1; o.z = m2; o.w = m3;
        }
        *(float4*)(mp + 4 * k) = o;
    }
}

__global__ __launch_bounds__(256, 4) void k_all(
    const float* __restrict__ x, const float* __restrict__ w, const float* __restrict__ bias,
    const float* __restrict__ gamma, const float* __restrict__ beta,
    float* __restrict__ y, float* __restrict__ MT,
    double2* __restrict__ npart, float2* __restrict__ spart)
{
    cg::grid_group grid = cg::this_grid();
    __shared__ __align__(16) float smem[4352];       // ring staging (4096) / pass_w merge (4224)
    __shared__ double dls[4], dlq[4];
    __shared__ double thrs[2];
    __shared__ double bnp[2];
    const int blk = blockIdx.x, t = threadIdx.x;

    // ---- phase 1: norm partials (channel-split, 2 threads per point) ----
    {
        int tid = blk * 256 + t;
        int ln = t & 63;
        int half = ln >> 5, lp = ln & 31;
        int p = (tid >> 6) * 32 + lp;
        int b = p >> 16, pp = p & 65535;
        int d = pp >> 11, h = (pp >> 6) & 31, wv2 = pp & 63;
        int pf = ((d ^ 16) << 11) | ((h ^ 16) << 6) | (wv2 ^ 32);
        const float* xb = x + (size_t)b * CDHW_ + (size_t)half * 16 * DHW_;
        double s = 0.0;
#pragma unroll
        for (int c = 0; c < 16; ++c) {
            float a  = xb[c * DHW_ + pp];
            float bb = xb[c * DHW_ + pf];
            s += fabs((double)a - (double)bb);
        }
        double st = s + __shfl_xor(s, 32, 64);
        double s2 = st * st;
        for (int off = 32; off; off >>= 1) {
            st += __shfl_down(st, off, 64);
            s2 += __shfl_down(s2, off, 64);
        }
        if (ln == 0) { dls[t >> 6] = st; dlq[t >> 6] = s2; }
        __syncthreads();
        if (t == 0) {
            double2 o;
            o.x = ((dls[0] + dls[1]) + (dls[2] + dls[3])) * 0.5;
            o.y = ((dlq[0] + dlq[1]) + (dlq[2] + dlq[3])) * 0.5;
            npart[blk] = o;
        }
    }
    __threadfence();
    grid.sync();

    // ---- phase 2: thr (redundant per block; bit-identical to k_thr) ----
    {
        double s = 0.0, q = 0.0;
#pragma unroll
        for (int i = 0; i < 4; ++i) {
            double2 v = npart[t * 4 + i];
            s += v.x; q += v.y;
        }
        for (int off = 32; off; off >>= 1) {
            s += __shfl_down(s, off, 64);
            q += __shfl_down(q, off, 64);
        }
        if ((t & 63) == 0) { dls[t >> 6] = s; dlq[t >> 6] = q; }
        __syncthreads();
        if (t < 2) {
            double sum = dls[2 * t] + dls[2 * t + 1];
            double sq  = dlq[2 * t] + dlq[2 * t + 1];
            double n = (double)NSP_;
            double mean = sum / n;
            double var = (sq - sum * sum / n) / (n - 1.0);
            if (var < 0.0) var = 0.0;
            thrs[t] = mean - sqrt(var);
        }
        __syncthreads();
    }

    // ---- phase 3: W pass — 2 waves per line, shift-range split, LDS max-merge ----
    {
        int wv = t >> 6, ln = t & 63;
        int ll = wv >> 1, role = wv & 1;
        int line = blk * 2 + ll;
        int b = line >> 10, d = (line >> 5) & 31, h = line & 31;
        double thr = thrs[b];
        const float* base = x + (size_t)b * CDHW_ + d * HW_ + h * W_ + ln;
        float col[32], Mv[32], nb[32];
#pragma unroll
        for (int c = 0; c < 32; ++c) { col[c] = base[c * DHW_]; Mv[c] = col[c]; }
        int sbeg = role ? 9 : 1, send = role ? 15 : 8;
        for (int si = sbeg; si <= send; ++si) {
            int srcf = (ln - 2 * si) & 63;
            int srcr = (ln + 2 * si) & 63;
#pragma unroll
            for (int c = 0; c < 32; ++c) nb[c] = __shfl(col[c], srcf, 64);
            float ds = dist32(col, nb);
            bool cmp = gate(ds, thr, col, nb);
#pragma unroll
            for (int c = 0; c < 32; ++c) Mv[c] = (cmp && nb[c] > Mv[c]) ? nb[c] : Mv[c];
            int cr = __shfl(cmp ? 1 : 0, srcr, 64);
#pragma unroll
            for (int c = 0; c < 32; ++c) nb[c] = __shfl(col[c], srcr, 64);
            bool cmpr = (cr != 0);
#pragma unroll
            for (int c = 0; c < 32; ++c) Mv[c] = (cmpr && nb[c] > Mv[c]) ? nb[c] : Mv[c];
        }
        if (role) {   // s = 16 (w-shift 32), self-paired
#pragma unroll
            for (int c = 0; c < 32; ++c) nb[c] = __shfl(col[c], ln ^ 32, 64);
            float ds = dist32(col, nb);
            bool cmp = gate(ds, thr, col, nb);
#pragma unroll
            for (int c = 0; c < 32; ++c) Mv[c] = (cmp && nb[c] > Mv[c]) ? nb[c] : Mv[c];
        }
        float* pwm = &smem[ll * 2112 + ln * 33];
        if (!role) {
#pragma unroll
            for (int c = 0; c < 32; ++c) pwm[c] = Mv[c];
        }
        __syncthreads();
        if (role) {
            float* mp = MT + ((size_t)b * 65536 + (size_t)d * HW_ + h * W_ + ln) * 32;
#pragma unroll
            for (int q = 0; q < 8; ++q) {
                float4 v;
                v.x = fmaxf(Mv[4*q+0], pwm[4*q+0]);
                v.y = fmaxf(Mv[4*q+1], pwm[4*q+1]);
                v.z = fmaxf(Mv[4*q+2], pwm[4*q+2]);
                v.w = fmaxf(Mv[4*q+3], pwm[4*q+3]);
                *(float4*)(mp + 4 * q) = v;
            }
        }
    }
    __threadfence();
    grid.sync();

    // ---- phase 4: H pass ----
    ring_phase<W_, false>(x, MT, thrs, smem, blk, t);
    __threadfence();
    grid.sync();

    // ---- phase 5: D pass (writes z2) ----
    ring_phase<HW_, true>(x, MT, thrs, smem, blk, t);
    __threadfence();
    grid.sync();

    // ---- phase 6: conv 64->32 + BN partials (4 waves x 8 outputs, 128 points/block) ----
    {
        int og = __builtin_amdgcn_readfirstlane(t >> 6);
        int pl = t & 63;
        int b = blk >> 9;
        int p0 = (blk & 511) * 128;
        const float* wo = w + og * 512;
        const float* bo = bias + og * 8;
        float s8[8], q8[8];
#pragma unroll
        for (int k = 0; k < 8; ++k) { s8[k] = 0.f; q8[k] = 0.f; }
#pragma unroll
        for (int grp = 0; grp < 2; ++grp) {
            int p = p0 + grp * 64 + pl;
            const float* xb = x + (size_t)b * CDHW_ + p;
            const float4* z2 = (const float4*)(MT + ((size_t)b * 65536 + p) * 32);
            float a[8];
#pragma unroll
            for (int k = 0; k < 8; ++k) a[k] = bo[k];
#pragma unroll
            for (int c = 0; c < 32; c += 4) {
                float z0 = xb[(size_t)(c+0) * DHW_];
                float z1 = xb[(size_t)(c+1) * DHW_];
                float zc2 = xb[(size_t)(c+2) * DHW_];
                float z3 = xb[(size_t)(c+3) * DHW_];
#pragma unroll
                for (int k = 0; k < 8; ++k) {
                    a[k] = fmaf(wo[k*64 + c+0], z0,  a[k]);
                    a[k] = fmaf(wo[k*64 + c+1], z1,  a[k]);
                    a[k] = fmaf(wo[k*64 + c+2], zc2, a[k]);
                    a[k] = fmaf(wo[k*64 + c+3], z3,  a[k]);
                }
            }
#pragma unroll
            for (int q = 0; q < 8; ++q) {
                float4 v = z2[q];
#pragma unroll
                for (int k = 0; k < 8; ++k) {
                    a[k] = fmaf(wo[k*64 + 32 + q*4 + 0], v.x, a[k]);
                    a[k] = fmaf(wo[k*64 + 32 + q*4 + 1], v.y, a[k]);
                    a[k] = fmaf(wo[k*64 + 32 + q*4 + 2], v.z, a[k]);
                    a[k] = fmaf(wo[k*64 + 32 + q*4 + 3], v.w, a[k]);
                }
            }
            float* yb = y + (size_t)b * CDHW_ + p;
#pragma unroll
            for (int k = 0; k < 8; ++k) {
                yb[(size_t)(og * 8 + k) * DHW_] = a[k];
                s8[k] += a[k];
                q8[k] += a[k] * a[k];
            }
        }
#pragma unroll
        for (int k = 0; k < 8; ++k) {
            float s = s8[k], q = q8[k];
            for (int off = 32; off; off >>= 1) {
                s += __shfl_down(s, off, 64);
                q += __shfl_down(q, off, 64);
            }
            if (pl == 0) spart[(og * 8 + k) * 1024 + blk] = make_float2(s, q);
        }
    }
    __threadfence();
    grid.sync();

    // ---- phase 7: BN finalize + GELU ----
    {
        int o = (blk >> 4) & 31;                     // wave-uniform channel for this y slab
        const float2* sp = spart + o * 1024;
        double s = 0.0, q = 0.0;
#pragma unroll
        for (int i = 0; i < 4; ++i) {
            float2 v = sp[i * 256 + t];
            s += (double)v.x; q += (double)v.y;
        }
        for (int off = 32; off; off >>= 1) {
            s += __shfl_down(s, off, 64);
            q += __shfl_down(q, off, 64);
        }
        if ((t & 63) == 0) { dls[t >> 6] = s; dlq[t >> 6] = q; }
        __syncthreads();
        if (t == 0) {
            double sm = (dls[0] + dls[1]) + (dls[2] + dls[3]);
            double sq = (dlq[0] + dlq[1]) + (dlq[2] + dlq[3]);
            double mu = sm / (double)BN_N_;
            double var = sq / (double)BN_N_ - mu * mu;
            bnp[0] = mu;
            bnp[1] = 1.0 / sqrt(var + 1e-5);
        }
        __syncthreads();
        float mu_f = (float)bnp[0], rstd = (float)bnp[1];
        float g = gamma[o], be = beta[o];
        float4* yv = (float4*)y;
#pragma unroll
        for (int i = 0; i < 4; ++i) {
            int idx = blk * 1024 + i * 256 + t;
            float4 v = yv[idx];
            float* vv = (float*)&v;
#pragma unroll
            for (int j = 0; j < 4; ++j) {
                float tt = (vv[j] - mu_f) * rstd * g + be;
                vv[j] = 0.5f * tt * (1.f + erff(tt * 0.70710678118654752f));
            }
            yv[idx] = v;
        }
    }
}

// ======================= fallback path (round-6 kernels, proven) =======================

__global__ __launch_bounds__(256) void k_norm(const float* __restrict__ x, double2* __restrict__ npart) {
    int tid = blockIdx.x * 256 + threadIdx.x;
    int ln = threadIdx.x & 63;
    int half = ln >> 5, lp = ln & 31;
    int p = (tid >> 6) * 32 + lp;
    int b = p >> 16, pp = p & 65535;
    int d = pp >> 11, h = (pp >> 6) & 31, w = pp & 63;
    int pf = ((d ^ 16) << 11) | ((h ^ 16) << 6) | (w ^ 32);
    const float* xb = x + (size_t)b * CDHW_ + (size_t)half * 16 * DHW_;
    double s = 0.0;
#pragma unroll
    for (int c = 0; c < 16; ++c) {
        float a  = xb[c * DHW_ + pp];
        float bb = xb[c * DHW_ + pf];
        s += fabs((double)a - (double)bb);
    }
    double st = s + __shfl_xor(s, 32, 64);
    double s2 = st * st;
    for (int off = 32; off; off >>= 1) {
        st += __shfl_down(st, off, 64);
        s2 += __shfl_down(s2, off, 64);
    }
    __shared__ double ls[4], ls2[4];
    int wv = threadIdx.x >> 6;
    if (ln == 0) { ls[wv] = st; ls2[wv] = s2; }
    __syncthreads();
    if (threadIdx.x == 0) {
        double2 o;
        o.x = ((ls[0] + ls[1]) + (ls[2] + ls[3])) * 0.5;
        o.y = ((ls2[0] + ls2[1]) + (ls2[2] + ls2[3])) * 0.5;
        npart[blockIdx.x] = o;
    }
}

__global__ __launch_bounds__(256) void k_thr(const double2* __restrict__ npart, double* __restrict__ thrp) {
    int t = threadIdx.x;
    double s = 0.0, q = 0.0;
#pragma unroll
    for (int i = 0; i < 4; ++i) {
        double2 v = npart[t * 4 + i];
        s += v.x; q += v.y;
    }
    for (int off = 32; off; off >>= 1) {
        s += __shfl_down(s, off, 64);
        q += __shfl_down(q, off, 64);
    }
    __shared__ double ls[4], lq[4];
    int wv = t >> 6;
    if ((t & 63) == 0) { ls[wv] = s; lq[wv] = q; }
    __syncthreads();
    if (t < 2) {
        double sum = ls[2 * t] + ls[2 * t + 1];
        double sq  = lq[2 * t] + lq[2 * t + 1];
        double n = (double)NSP_;
        double mean = sum / n;
        double var = (sq - sum * sum / n) / (n - 1.0);
        if (var < 0.0) var = 0.0;
        thrp[t] = mean - sqrt(var);
    }
}

__global__ __launch_bounds__(256) void k_pass_w(const float* __restrict__ x, const double* __restrict__ thrp,
                                                float* __restrict__ MT) {
    int wvg = blockIdx.x * 4 + (threadIdx.x >> 6);
    int ln = threadIdx.x & 63;
    int b = wvg >> 10, d = (wvg >> 5) & 31, h = wvg & 31;
    double thr = thrp[b];
    const float* base = x + (size_t)b * CDHW_ + d * HW_ + h * W_ + ln;
    float col[32], Mv[32], nb[32];
#pragma unroll
    for (int c = 0; c < 32; ++c) { col[c] = base[c * DHW_]; Mv[c] = col[c]; }
    for (int si = 1; si <= 15; ++si) {
        int srcf = (ln - 2 * si) & 63;
        int srcr = (ln + 2 * si) & 63;
#pragma unroll
        for (int c = 0; c < 32; ++c) nb[c] = __shfl(col[c], srcf, 64);
        float ds = dist32(col, nb);
        bool cmp = gate(ds, thr, col, nb);
#pragma unroll
        for (int c = 0; c < 32; ++c) Mv[c] = (cmp && nb[c] > Mv[c]) ? nb[c] : Mv[c];
        int cr = __shfl(cmp ? 1 : 0, srcr, 64);
#pragma unroll
        for (int c = 0; c < 32; ++c) nb[c] = __shfl(col[c], srcr, 64);
        bool cmpr = (cr != 0);
#pragma unroll
        for (int c = 0; c < 32; ++c) Mv[c] = (cmpr && nb[c] > Mv[c]) ? nb[c] : Mv[c];
    }
    {
#pragma unroll
        for (int c = 0; c < 32; ++c) nb[c] = __shfl(col[c], ln ^ 32, 64);
        float ds = dist32(col, nb);
        bool cmp = gate(ds, thr, col, nb);
#pragma unroll
        for (int c = 0; c < 32; ++c) Mv[c] = (cmp && nb[c] > Mv[c]) ? nb[c] : Mv[c];
    }
    float* mp = MT + ((size_t)b * 65536 + (size_t)d * HW_ + h * W_ + ln) * 32;
#pragma unroll
    for (int q = 0; q < 8; ++q) {
        float4 v; v.x = Mv[4*q]; v.y = Mv[4*q+1]; v.z = Mv[4*q+2]; v.w = Mv[4*q+3];
        *(float4*)(mp + 4 * q) = v;
    }
}

template<int AS, int FS, bool Z2T>
__global__ __launch_bounds__(512) void k_ring(const float* __restrict__ x, const double* __restrict__ thrp,
                                              float* __restrict__ MT) {
    __shared__ __align__(16) float L[8192];
    int t = threadIdx.x;
    int w0 = blockIdx.x * 8;
    int F = blockIdx.y;
    int b = blockIdx.z;
    double thr = thrp[b];
    const float* xb = x + (size_t)b * CDHW_ + (size_t)F * FS + w0;
#pragma unroll
    for (int it = 0; it < 4; ++it) {
        int f = it * 512 + t;
        int a = f >> 6, c = (f >> 1) & 31, wq = f & 1;
        float4 v = *(const float4*)(xb + (size_t)c * DHW_ + (size_t)a * AS + wq * 4);
        int j = a >> 1, par = a & 1;
        int sl = (((c >> 2) ^ (j & 7)) << 2) + (c & 3);
        int rb = (par * 8 + wq * 4) * 512 + j * 32 + sl;
        L[rb] = v.x; L[rb + 512] = v.y; L[rb + 1024] = v.z; L[rb + 1536] = v.w;
    }
    __syncthreads();
    int wl = t & 7, half = (t >> 3) & 1, pos = (t >> 4) & 15, par = t >> 8;
    int ring = par * 8 + wl;
    const float* Lr = L + ring * 512;
    int qb = half * 4;
    float col[16], Mv[16], nb[16];
#pragma unroll
    for (int k = 0; k < 4; ++k) {
        float4 cv = *(const float4*)(Lr + pos * 32 + (((qb + k) ^ (pos & 7)) << 2));
        col[4*k] = cv.x; col[4*k+1] = cv.y; col[4*k+2] = cv.z; col[4*k+3] = cv.w;
    }
#pragma unroll
    for (int c = 0; c < 16; ++c) Mv[c] = col[c];
    for (int s = 1; s < 16; ++s) {
        int jj = (pos - s) & 15;
#pragma unroll
        for (int k = 0; k < 4; ++k) {
            float4 nv = *(const float4*)(Lr + jj * 32 + (((qb + k) ^ (jj & 7)) << 2));
            nb[4*k] = nv.x; nb[4*k+1] = nv.y; nb[4*k+2] = nv.z; nb[4*k+3] = nv.w;
        }
        float dh = dist16(col, nb);
        float ds = dh + __shfl_xor(dh, 8, 64);
        bool cmp;
        bool border = fabs((double)ds - thr) < BORDER;
        if (__ballot(border)) {
            double d64h = 0.0;
#pragma unroll
            for (int c = 0; c < 16; ++c) d64h += fabs((double)col[c] - (double)nb[c]);
            double other = __shfl_xor(d64h, 8, 64);
            cmp = (d64h + other) < thr;
        } else {
            cmp = (double)ds < thr;
        }
#pragma unroll
        for (int c = 0; c < 16; ++c) Mv[c] = (cmp && nb[c] > Mv[c]) ? nb[c] : Mv[c];
    }
    size_t p = (size_t)F * FS + (size_t)(2 * pos + par) * AS + w0 + wl;
    float* mp = MT + ((size_t)b * 65536 + p) * 32 + half * 16;
#pragma unroll
    for (int k = 0; k < 4; ++k) {
        float4 old = *(const float4*)(mp + 4 * k);
        float m0 = fmaxf(old.x, Mv[4*k]);   float m1 = fmaxf(old.y, Mv[4*k+1]);
        float m2 = fmaxf(old.z, Mv[4*k+2]); float m3 = fmaxf(old.w, Mv[4*k+3]);
        float4 o;
        if (Z2T) {
            o.x = fmaxf(m0 - col[4*k],   0.f); o.y = fmaxf(m1 - col[4*k+1], 0.f);
            o.z = fmaxf(m2 - col[4*k+2], 0.f); o.w = fmaxf(m3 - col[4*k+3], 0.f);
        } else {
            o.x = m0; o.y = m1; o.z = m2; o.w = m3;
        }
        *(float4*)(mp + 4 * k) = o;
    }
}

__global__ __launch_bounds__(256, 4) void k_conv(const float* __restrict__ x, const float* __restrict__ Z2,
                                                 const float* __restrict__ w, const float* __restrict__ bias,
                                                 float* __restrict__ y) {
    int t = threadIdx.x;
    int blk = blockIdx.x;
    int b = blk >> 10;
    int p0 = (blk & 1023) * 64;
    int og = __builtin_amdgcn_readfirstlane(t >> 6);
    int pl = t & 63;
    const float* xb = x + (size_t)b * CDHW_ + p0 + pl;
    const float4* z2 = (const float4*)(Z2 + ((size_t)b * 65536 + p0 + pl) * 32);
    const float* wo = w + og * 8 * 64;
    const float* bo = bias + og * 8;
    float a[8];
#pragma unroll
    for (int k = 0; k < 8; ++k) a[k] = bo[k];
#pragma unroll
    for (int c = 0; c < 32; c += 4) {
        float z0 = xb[(size_t)(c+0) * DHW_];
        float z1 = xb[(size_t)(c+1) * DHW_];
        float zc2 = xb[(size_t)(c+2) * DHW_];
        float z3 = xb[(size_t)(c+3) * DHW_];
#pragma unroll
        for (int k = 0; k < 8; ++k) {
            a[k] = fmaf(wo[k*64 + c+0], z0,  a[k]);
            a[k] = fmaf(wo[k*64 + c+1], z1,  a[k]);
            a[k] = fmaf(wo[k*64 + c+2], zc2, a[k]);
            a[k] = fmaf(wo[k*64 + c+3], z3,  a[k]);
        }
    }
#pragma unroll
    for (int q = 0; q < 8; ++q) {
        float4 v = z2[q];
#pragma unroll
        for (int k = 0; k < 8; ++k) {
            a[k] = fmaf(wo[k*64 + 32 + q*4 + 0], v.x, a[k]);
            a[k] = fmaf(wo[k*64 + 32 + q*4 + 1], v.y, a[k]);
            a[k] = fmaf(wo[k*64 + 32 + q*4 + 2], v.z, a[k]);
            a[k] = fmaf(wo[k*64 + 32 + q*4 + 3], v.w, a[k]);
        }
    }
    float* yb = y + (size_t)b * CDHW_ + p0 + pl;
#pragma unroll
    for (int k = 0; k < 8; ++k) yb[(size_t)(og * 8 + k) * DHW_] = a[k];
}

__global__ __launch_bounds__(256) void k_stats(const float* __restrict__ y, double2* __restrict__ spart) {
    int o = blockIdx.y, ch = blockIdx.x;
    float s = 0.f, q = 0.f;
#pragma unroll
    for (int b = 0; b < 2; ++b) {
        const float4* yp = (const float4*)(y + (size_t)b * CDHW_ + (size_t)o * DHW_ + ch * 4096);
#pragma unroll
        for (int i = 0; i < 4; ++i) {
            float4 v = yp[i * 256 + threadIdx.x];
            s += ((v.x + v.y) + (v.z + v.w));
            q += ((v.x*v.x + v.y*v.y) + (v.z*v.z + v.w*v.w));
        }
    }
    double sd = s, qd = q;
    for (int off = 32; off; off >>= 1) {
        sd += __shfl_down(sd, off, 64);
        qd += __shfl_down(qd, off, 64);
    }
    __shared__ double ls[4], lq[4];
    int wv = threadIdx.x >> 6;
    if ((threadIdx.x & 63) == 0) { ls[wv] = sd; lq[wv] = qd; }
    __syncthreads();
    if (threadIdx.x == 0) {
        double2 out;
        out.x = (ls[0] + ls[1]) + (ls[2] + ls[3]);
        out.y = (lq[0] + lq[1]) + (lq[2] + lq[3]);
        spart[o * 16 + ch] = out;
    }
}

__global__ __launch_bounds__(256) void k_out(float* __restrict__ y, const double2* __restrict__ spart,
                                             const float* __restrict__ gamma, const float* __restrict__ beta) {
    int idx = blockIdx.x * 256 + threadIdx.x;
    int o = (blockIdx.x >> 6) & 31;
    double sm = 0.0, sq = 0.0;
#pragma unroll
    for (int ch = 0; ch < 16; ++ch) {
        double2 v = spart[o * 16 + ch];
        sm += v.x; sq += v.y;
    }
    double mu = sm / (double)BN_N_;
    double var = sq / (double)BN_N_ - mu * mu;
    float rstd = (float)(1.0 / sqrt(var + 1e-5));
    float mu_f = (float)mu;
    float g = gamma[o], be = beta[o];
    float4 v = ((const float4*)y)[idx];
    float* vv = (float*)&v;
#pragma unroll
    for (int j = 0; j < 4; ++j) {
        float t = (vv[j] - mu_f) * rstd * g + be;
        vv[j] = 0.5f * t * (1.f + erff(t * 0.70710678118654752f));
    }
    ((float4*)y)[idx] = v;
}

extern "C" void kernel_launch(void* const* d_in, const int* in_sizes, int n_in,
                              void* d_out, int out_size, void* d_ws, size_t ws_size,
                              hipStream_t stream) {
    const float* x     = (const float*)d_in[0];
    const float* w     = (const float*)d_in[1];
    const float* bias  = (const float*)d_in[2];
    const float* gamma = (const float*)d_in[3];
    const float* beta  = (const float*)d_in[4];
    float* out = (float*)d_out;
    float* MT  = (float*)d_ws;
    double*  thrp   = (double*)((char*)d_ws + ACC_OFF);
    double2* npart  = (double2*)((char*)d_ws + ACC_OFF + 256);
    float2*  spartf = (float2*)((char*)d_ws + ACC_OFF + 256 + 16384);
    double2* spartd = (double2*)((char*)d_ws + ACC_OFF + 256 + 16384);

    void* args[] = {(void*)&x, (void*)&w, (void*)&bias, (void*)&gamma, (void*)&beta,
                    (void*)&out, (void*)&MT, (void*)&npart, (void*)&spartf};
    hipError_t e = hipLaunchCooperativeKernel((void*)k_all, dim3(1024), dim3(256), args, 0, stream);
    if (e != hipSuccess) {
        // fallback: proven round-6 pipeline
        k_norm  <<<1024, 256, 0, stream>>>(x, npart);
        k_thr   <<<1, 256, 0, stream>>>(npart, thrp);
        k_pass_w<<<512, 256, 0, stream>>>(x, thrp, MT);
        k_ring<W_,  HW_, false><<<dim3(8, 32, 2), 512, 0, stream>>>(x, thrp, MT);
        k_ring<HW_, W_,  true ><<<dim3(8, 32, 2), 512, 0, stream>>>(x, thrp, MT);
        k_conv  <<<2048, 256, 0, stream>>>(x, MT, w, bias, out);
        k_stats <<<dim3(16, 32), 256, 0, stream>>>(out, spartd);
        k_out   <<<4096, 256, 0, stream>>>(out, spartd, gamma, beta);
    }
}

// Round 8
// 128.886 us; speedup vs baseline: 8.9399x; 8.9399x over previous
//
#include <hip/hip_runtime.h>
#include <math.h>

#define B_ 2
#define C_ 32
#define D_ 32
#define H_ 32
#define W_ 64
#define HW_ (H_*W_)         // 2048
#define DHW_ (D_*H_*W_)     // 65536
#define CDHW_ (C_*DHW_)     // 2097152
#define NSP_ DHW_           // spatial points per batch
#define BN_N_ (B_*DHW_)     // 131072
#define ACC_OFF 16777216    // byte offset of reduction area in ws (after MT)
#define BORDER 1e-3

// ws: MT [b][p][c] 16MB (after ring-D holds z2 = relu(M-x)); at ACC_OFF:
//   npart[1024] double2 at +256 (per-block norm partials {sum,sumsq})
//   spart[512]  double2 at +256+16384 (per-block BN partials)
// Every slot written before read each call -> no zeroing (poison-safe).

// ---------------- threshold stats (channel-split: 2 threads per point) ----------------
__global__ __launch_bounds__(256) void k_norm(const float* __restrict__ x, double2* __restrict__ npart) {
    int tid = blockIdx.x * 256 + threadIdx.x;       // 262144 threads
    int ln = threadIdx.x & 63;
    int half = ln >> 5, lp = ln & 31;
    int p = (tid >> 6) * 32 + lp;                   // 131072 points, 2x coverage
    int b = p >> 16, pp = p & 65535;
    int d = pp >> 11, h = (pp >> 6) & 31, w = pp & 63;
    int pf = ((d ^ 16) << 11) | ((h ^ 16) << 6) | (w ^ 32);
    const float* xb = x + (size_t)b * CDHW_ + (size_t)half * 16 * DHW_;
    double s = 0.0;
#pragma unroll
    for (int c = 0; c < 16; ++c) {
        float a  = xb[c * DHW_ + pp];
        float bb = xb[c * DHW_ + pf];
        s += fabs((double)a - (double)bb);
    }
    double st = s + __shfl_xor(s, 32, 64);          // full 32-ch sum (both halves hold it)
    double s2 = st * st;
    for (int off = 32; off; off >>= 1) {
        st += __shfl_down(st, off, 64);
        s2 += __shfl_down(s2, off, 64);
    }
    __shared__ double ls[4], ls2[4];
    int wv = threadIdx.x >> 6;
    if (ln == 0) { ls[wv] = st; ls2[wv] = s2; }
    __syncthreads();
    if (threadIdx.x == 0) {                          // each point counted twice -> *0.5 (exact)
        double2 o;
        o.x = ((ls[0] + ls[1]) + (ls[2] + ls[3])) * 0.5;
        o.y = ((ls2[0] + ls2[1]) + (ls2[2] + ls2[3])) * 0.5;
        npart[blockIdx.x] = o;
    }
}

// ---------------- per-block redundant thr reduce (replaces the 1-block k_thr dispatch) ----------------
// waves 0..3 (t<256) reduce npart[1024] -> thrs[2] in shared. All block threads must call.
__device__ __forceinline__ void thr_reduce(const double2* __restrict__ npart, double* thrs,
                                           double* ls, double* lq, int t) {
    if (t < 256) {
        double s = 0.0, q = 0.0;
#pragma unroll
        for (int i = 0; i < 4; ++i) {
            double2 v = npart[t * 4 + i];
            s += v.x; q += v.y;
        }
        for (int off = 32; off; off >>= 1) {
            s += __shfl_down(s, off, 64);
            q += __shfl_down(q, off, 64);
        }
        if ((t & 63) == 0) { ls[t >> 6] = s; lq[t >> 6] = q; }
    }
    __syncthreads();
    if (t < 2) {
        double sum = ls[2 * t] + ls[2 * t + 1];
        double sq  = lq[2 * t] + lq[2 * t + 1];
        double n = (double)NSP_;
        double mean = sum / n;
        double var = (sq - sum * sum / n) / (n - 1.0);   // ddof=1
        if (var < 0.0) var = 0.0;
        thrs[t] = mean - sqrt(var);
    }
    __syncthreads();
}

__device__ __forceinline__ float dist32(const float* col, const float* nb) {
    float d0 = 0.f, d1 = 0.f, d2 = 0.f, d3 = 0.f;
#pragma unroll
    for (int c = 0; c < 32; c += 4) {
        d0 += fabsf(col[c+0] - nb[c+0]);
        d1 += fabsf(col[c+1] - nb[c+1]);
        d2 += fabsf(col[c+2] - nb[c+2]);
        d3 += fabsf(col[c+3] - nb[c+3]);
    }
    return (d0 + d1) + (d2 + d3);
}

__device__ __forceinline__ float dist16(const float* col, const float* nb) {
    float d0 = 0.f, d1 = 0.f, d2 = 0.f, d3 = 0.f;
#pragma unroll
    for (int c = 0; c < 16; c += 4) {
        d0 += fabsf(col[c+0] - nb[c+0]);
        d1 += fabsf(col[c+1] - nb[c+1]);
        d2 += fabsf(col[c+2] - nb[c+2]);
        d3 += fabsf(col[c+3] - nb[c+3]);
    }
    return (d0 + d1) + (d2 + d3);
}

__device__ __forceinline__ bool gate(float ds, double thr, const float* col, const float* nb) {
    bool border = fabs((double)ds - thr) < BORDER;
    if (__ballot(border)) {
        double d64 = 0.0;
#pragma unroll
        for (int c = 0; c < 32; ++c) d64 += fabs((double)col[c] - (double)nb[c]);
        return d64 < thr;
    }
    return (double)ds < thr;
}

// ---------------- W pass: 2 waves per line (role-split shifts), LDS max-merge ----------------
// 1024 blocks x 256 threads; block covers 2 lines; role 0: si 1..8, role 1: si 9..15 + s16.
__global__ __launch_bounds__(256) void k_pass_w(const float* __restrict__ x, const double2* __restrict__ npart,
                                                float* __restrict__ MT) {
    __shared__ float pw[4224];
    __shared__ double ls[4], lq[4], thrs[2];
    int t = threadIdx.x;
    thr_reduce(npart, thrs, ls, lq, t);
    int wv = t >> 6, ln = t & 63;
    int ll = wv >> 1, role = wv & 1;
    int line = blockIdx.x * 2 + ll;                  // 0..2047
    int b = line >> 10, d = (line >> 5) & 31, h = line & 31;
    double thr = thrs[b];
    const float* base = x + (size_t)b * CDHW_ + d * HW_ + h * W_ + ln;
    float col[32], Mv[32], nb[32];
#pragma unroll
    for (int c = 0; c < 32; ++c) { col[c] = base[c * DHW_]; Mv[c] = col[c]; }
    int sbeg = role ? 9 : 1, send = role ? 15 : 8;
    for (int si = sbeg; si <= send; ++si) {
        int srcf = (ln - 2 * si) & 63;
        int srcr = (ln + 2 * si) & 63;
#pragma unroll
        for (int c = 0; c < 32; ++c) nb[c] = __shfl(col[c], srcf, 64);
        float ds = dist32(col, nb);
        bool cmp = gate(ds, thr, col, nb);
#pragma unroll
        for (int c = 0; c < 32; ++c) Mv[c] = (cmp && nb[c] > Mv[c]) ? nb[c] : Mv[c];
        int cr = __shfl(cmp ? 1 : 0, srcr, 64);      // pair symmetry: partner's decision
#pragma unroll
        for (int c = 0; c < 32; ++c) nb[c] = __shfl(col[c], srcr, 64);
        bool cmpr = (cr != 0);
#pragma unroll
        for (int c = 0; c < 32; ++c) Mv[c] = (cmpr && nb[c] > Mv[c]) ? nb[c] : Mv[c];
    }
    if (role) {   // s = 16 (w-shift 32), self-paired
#pragma unroll
        for (int c = 0; c < 32; ++c) nb[c] = __shfl(col[c], ln ^ 32, 64);
        float ds = dist32(col, nb);
        bool cmp = gate(ds, thr, col, nb);
#pragma unroll
        for (int c = 0; c < 32; ++c) Mv[c] = (cmp && nb[c] > Mv[c]) ? nb[c] : Mv[c];
    }
    float* pwm = &pw[ll * 2112 + ln * 33];
    if (!role) {
#pragma unroll
        for (int c = 0; c < 32; ++c) pwm[c] = Mv[c];
    }
    __syncthreads();
    if (role) {
        float* mp = MT + ((size_t)b * 65536 + (size_t)d * HW_ + h * W_ + ln) * 32;
#pragma unroll
        for (int q = 0; q < 8; ++q) {
            float4 v;
            v.x = fmaxf(Mv[4*q+0], pwm[4*q+0]);
            v.y = fmaxf(Mv[4*q+1], pwm[4*q+1]);
            v.z = fmaxf(Mv[4*q+2], pwm[4*q+2]);
            v.w = fmaxf(Mv[4*q+3], pwm[4*q+3]);
            *(float4*)(mp + 4 * q) = v;
        }
    }
}

// ---------------- LDS ring pass, channel-split (H or D axis) ----------------
template<int AS, int FS, bool Z2T>
__global__ __launch_bounds__(512) void k_ring(const float* __restrict__ x, const double2* __restrict__ npart,
                                              float* __restrict__ MT) {
    __shared__ __align__(16) float L[8192];          // 32 KB
    __shared__ double ls[4], lq[4], thrs[2];
    int t = threadIdx.x;
    thr_reduce(npart, thrs, ls, lq, t);
    int w0 = blockIdx.x * 8;
    int F = blockIdx.y;
    int b = blockIdx.z;
    double thr = thrs[b];
    const float* xb = x + (size_t)b * CDHW_ + (size_t)F * FS + w0;
#pragma unroll
    for (int it = 0; it < 4; ++it) {
        int f = it * 512 + t;                        // 0..2047 float4s
        int a = f >> 6, c = (f >> 1) & 31, wq = f & 1;
        float4 v = *(const float4*)(xb + (size_t)c * DHW_ + (size_t)a * AS + wq * 4);
        int j = a >> 1, par = a & 1;
        int sl = (((c >> 2) ^ (j & 7)) << 2) + (c & 3);
        int rb = (par * 8 + wq * 4) * 512 + j * 32 + sl;
        L[rb] = v.x; L[rb + 512] = v.y; L[rb + 1024] = v.z; L[rb + 1536] = v.w;
    }
    __syncthreads();
    int wl = t & 7, half = (t >> 3) & 1, pos = (t >> 4) & 15, par = t >> 8;
    int ring = par * 8 + wl;
    const float* Lr = L + ring * 512;
    int qb = half * 4;
    float col[16], Mv[16], nb[16];
#pragma unroll
    for (int k = 0; k < 4; ++k) {
        float4 cv = *(const float4*)(Lr + pos * 32 + (((qb + k) ^ (pos & 7)) << 2));
        col[4*k] = cv.x; col[4*k+1] = cv.y; col[4*k+2] = cv.z; col[4*k+3] = cv.w;
    }
#pragma unroll
    for (int c = 0; c < 16; ++c) Mv[c] = col[c];
    for (int s = 1; s < 16; ++s) {
        int jj = (pos - s) & 15;
#pragma unroll
        for (int k = 0; k < 4; ++k) {
            float4 nv = *(const float4*)(Lr + jj * 32 + (((qb + k) ^ (jj & 7)) << 2));
            nb[4*k] = nv.x; nb[4*k+1] = nv.y; nb[4*k+2] = nv.z; nb[4*k+3] = nv.w;
        }
        float dh = dist16(col, nb);
        float ds = dh + __shfl_xor(dh, 8, 64);       // combine the two 16-ch halves
        bool cmp;
        bool border = fabs((double)ds - thr) < BORDER;
        if (__ballot(border)) {                      // rare fp64 path: exchange f64 partials
            double d64h = 0.0;
#pragma unroll
            for (int c = 0; c < 16; ++c) d64h += fabs((double)col[c] - (double)nb[c]);
            double other = __shfl_xor(d64h, 8, 64);
            cmp = (d64h + other) < thr;
        } else {
            cmp = (double)ds < thr;
        }
#pragma unroll
        for (int c = 0; c < 16; ++c) Mv[c] = (cmp && nb[c] > Mv[c]) ? nb[c] : Mv[c];
    }
    size_t p = (size_t)F * FS + (size_t)(2 * pos + par) * AS + w0 + wl;
    float* mp = MT + ((size_t)b * 65536 + p) * 32 + half * 16;
#pragma unroll
    for (int k = 0; k < 4; ++k) {
        float4 old = *(const float4*)(mp + 4 * k);
        float m0 = fmaxf(old.x, Mv[4*k]);   float m1 = fmaxf(old.y, Mv[4*k+1]);
        float m2 = fmaxf(old.z, Mv[4*k+2]); float m3 = fmaxf(old.w, Mv[4*k+3]);
        float4 o;
        if (Z2T) {   // final pass: store z2 = relu(M - x)
            o.x = fmaxf(m0 - col[4*k],   0.f); o.y = fmaxf(m1 - col[4*k+1], 0.f);
            o.z = fmaxf(m2 - col[4*k+2], 0.f); o.w = fmaxf(m3 - col[4*k+3], 0.f);
        } else {
            o.x = m0; o.y = m1; o.z = m2; o.w = m3;
        }
        *(float4*)(mp + 4 * k) = o;
    }
}

// ---------------- 1x1x1 conv (64 -> 32); 4 waves per 64-point tile, 8 outputs/wave ----------------
__global__ __launch_bounds__(256, 4) void k_conv(const float* __restrict__ x, const float* __restrict__ Z2,
                                                 const float* __restrict__ w, const float* __restrict__ bias,
                                                 float* __restrict__ y) {
    int t = threadIdx.x;
    int blk = blockIdx.x;                            // 0..2047
    int b = blk >> 10;
    int p0 = (blk & 1023) * 64;
    int og = __builtin_amdgcn_readfirstlane(t >> 6); // wave-uniform -> weights stay scalar
    int pl = t & 63;
    const float* xb = x + (size_t)b * CDHW_ + p0 + pl;
    const float4* z2 = (const float4*)(Z2 + ((size_t)b * 65536 + p0 + pl) * 32);
    const float* wo = w + og * 8 * 64;               // SGPR base -> s_load weights
    const float* bo = bias + og * 8;
    float a[8];
#pragma unroll
    for (int k = 0; k < 8; ++k) a[k] = bo[k];
#pragma unroll
    for (int c = 0; c < 32; c += 4) {                // x half (L1-reused across the 4 waves)
        float z0 = xb[(size_t)(c+0) * DHW_];
        float z1 = xb[(size_t)(c+1) * DHW_];
        float zc2 = xb[(size_t)(c+2) * DHW_];
        float z3 = xb[(size_t)(c+3) * DHW_];
#pragma unroll
        for (int k = 0; k < 8; ++k) {
            a[k] = fmaf(wo[k*64 + c+0], z0,  a[k]);
            a[k] = fmaf(wo[k*64 + c+1], z1,  a[k]);
            a[k] = fmaf(wo[k*64 + c+2], zc2, a[k]);
            a[k] = fmaf(wo[k*64 + c+3], z3,  a[k]);
        }
    }
#pragma unroll
    for (int q = 0; q < 8; ++q) {                    // z2 half (contiguous 128B/point)
        float4 v = z2[q];
#pragma unroll
        for (int k = 0; k < 8; ++k) {
            a[k] = fmaf(wo[k*64 + 32 + q*4 + 0], v.x, a[k]);
            a[k] = fmaf(wo[k*64 + 32 + q*4 + 1], v.y, a[k]);
            a[k] = fmaf(wo[k*64 + 32 + q*4 + 2], v.z, a[k]);
            a[k] = fmaf(wo[k*64 + 32 + q*4 + 3], v.w, a[k]);
        }
    }
    float* yb = y + (size_t)b * CDHW_ + p0 + pl;
#pragma unroll
    for (int k = 0; k < 8; ++k) yb[(size_t)(og * 8 + k) * DHW_] = a[k];
}

// ---------------- BN batch stats from y -> per-block partials ----------------
__global__ __launch_bounds__(256) void k_stats(const float* __restrict__ y, double2* __restrict__ spart) {
    int o = blockIdx.y, ch = blockIdx.x;
    float s = 0.f, q = 0.f;
#pragma unroll
    for (int b = 0; b < 2; ++b) {
        const float4* yp = (const float4*)(y + (size_t)b * CDHW_ + (size_t)o * DHW_ + ch * 4096);
#pragma unroll
        for (int i = 0; i < 4; ++i) {
            float4 v = yp[i * 256 + threadIdx.x];
            s += ((v.x + v.y) + (v.z + v.w));
            q += ((v.x*v.x + v.y*v.y) + (v.z*v.z + v.w*v.w));
        }
    }
    double sd = s, qd = q;
    for (int off = 32; off; off >>= 1) {
        sd += __shfl_down(sd, off, 64);
        qd += __shfl_down(qd, off, 64);
    }
    __shared__ double ls[4], lq[4];
    int wv = threadIdx.x >> 6;
    if ((threadIdx.x & 63) == 0) { ls[wv] = sd; lq[wv] = qd; }
    __syncthreads();
    if (threadIdx.x == 0) {
        double2 out;
        out.x = (ls[0] + ls[1]) + (ls[2] + ls[3]);
        out.y = (lq[0] + lq[1]) + (lq[2] + lq[3]);
        spart[o * 16 + ch] = out;
    }
}

// ---------------- BN normalize + exact GELU, in-place ----------------
__global__ __launch_bounds__(256) void k_out(float* __restrict__ y, const double2* __restrict__ spart,
                                             const float* __restrict__ gamma, const float* __restrict__ beta) {
    int idx = blockIdx.x * 256 + threadIdx.x;       // over 1,048,576 float4
    int o = (blockIdx.x >> 6) & 31;                  // wave-uniform channel
    double sm = 0.0, sq = 0.0;
#pragma unroll
    for (int ch = 0; ch < 16; ++ch) {
        double2 v = spart[o * 16 + ch];
        sm += v.x; sq += v.y;
    }
    double mu = sm / (double)BN_N_;
    double var = sq / (double)BN_N_ - mu * mu;
    float rstd = (float)(1.0 / sqrt(var + 1e-5));
    float mu_f = (float)mu;
    float g = gamma[o], be = beta[o];
    float4 v = ((const float4*)y)[idx];
    float* vv = (float*)&v;
#pragma unroll
    for (int j = 0; j < 4; ++j) {
        float t = (vv[j] - mu_f) * rstd * g + be;
        vv[j] = 0.5f * t * (1.f + erff(t * 0.70710678118654752f));
    }
    ((float4*)y)[idx] = v;
}

extern "C" void kernel_launch(void* const* d_in, const int* in_sizes, int n_in,
                              void* d_out, int out_size, void* d_ws, size_t ws_size,
                              hipStream_t stream) {
    const float* x     = (const float*)d_in[0];
    const float* w     = (const float*)d_in[1];
    const float* bias  = (const float*)d_in[2];
    const float* gamma = (const float*)d_in[3];
    const float* beta  = (const float*)d_in[4];
    float* out = (float*)d_out;
    float* MT  = (float*)d_ws;                       // [b][p][c]; holds z2 after ring-D
    double2* npart = (double2*)((char*)d_ws + ACC_OFF + 256);
    double2* spart = (double2*)((char*)d_ws + ACC_OFF + 256 + 16384);

    k_norm  <<<1024, 256, 0, stream>>>(x, npart);
    k_pass_w<<<1024, 256, 0, stream>>>(x, npart, MT);
    k_ring<W_,  HW_, false><<<dim3(8, 32, 2), 512, 0, stream>>>(x, npart, MT);   // H pass (F = d)
    k_ring<HW_, W_,  true ><<<dim3(8, 32, 2), 512, 0, stream>>>(x, npart, MT);   // D pass (F = h), writes z2
    k_conv  <<<2048, 256, 0, stream>>>(x, MT, w, bias, out);
    k_stats <<<dim3(16, 32), 256, 0, stream>>>(out, spart);
    k_out   <<<4096, 256, 0, stream>>>(out, spart, gamma, beta);
}

// Round 9
// 116.787 us; speedup vs baseline: 9.8661x; 1.1036x over previous
//
#include <hip/hip_runtime.h>
#include <math.h>

#define B_ 2
#define C_ 32
#define D_ 32
#define H_ 32
#define W_ 64
#define HW_ (H_*W_)         // 2048
#define DHW_ (D_*H_*W_)     // 65536
#define CDHW_ (C_*DHW_)     // 2097152
#define NSP_ DHW_           // spatial points per batch
#define BN_N_ (B_*DHW_)     // 131072
#define BORDER 1e-3

// ws layout: Mw [b][p][c] @0 (16MB), Mh @16MB, Md @32MB (each pure-write, transposed [b][p][32]),
// reduction area @48MB: npart[1024] double2 @ +256, spart[512] double2 @ +256+16384.
// Every slot written before read each call -> no zeroing (poison-safe).
#define MH_OFF  (16u<<20)
#define MD_OFF  (32u<<20)
#define RED_OFF (48u<<20)

// ---------------- threshold stats (channel-split: 2 threads per point) ----------------
__global__ __launch_bounds__(256) void k_norm(const float* __restrict__ x, double2* __restrict__ npart) {
    int tid = blockIdx.x * 256 + threadIdx.x;       // 262144 threads
    int ln = threadIdx.x & 63;
    int half = ln >> 5, lp = ln & 31;
    int p = (tid >> 6) * 32 + lp;                   // 131072 points, 2x coverage
    int b = p >> 16, pp = p & 65535;
    int d = pp >> 11, h = (pp >> 6) & 31, w = pp & 63;
    int pf = ((d ^ 16) << 11) | ((h ^ 16) << 6) | (w ^ 32);
    const float* xb = x + (size_t)b * CDHW_ + (size_t)half * 16 * DHW_;
    double s = 0.0;
#pragma unroll
    for (int c = 0; c < 16; ++c) {
        float a  = xb[c * DHW_ + pp];
        float bb = xb[c * DHW_ + pf];
        s += fabs((double)a - (double)bb);
    }
    double st = s + __shfl_xor(s, 32, 64);          // full 32-ch sum (both halves hold it)
    double s2 = st * st;
    for (int off = 32; off; off >>= 1) {
        st += __shfl_down(st, off, 64);
        s2 += __shfl_down(s2, off, 64);
    }
    __shared__ double ls[4], ls2[4];
    int wv = threadIdx.x >> 6;
    if (ln == 0) { ls[wv] = st; ls2[wv] = s2; }
    __syncthreads();
    if (threadIdx.x == 0) {                          // each point counted twice -> *0.5 (exact)
        double2 o;
        o.x = ((ls[0] + ls[1]) + (ls[2] + ls[3])) * 0.5;
        o.y = ((ls2[0] + ls2[1]) + (ls2[2] + ls2[3])) * 0.5;
        npart[blockIdx.x] = o;
    }
}

// ---------------- per-block redundant thr reduce ----------------
__device__ __forceinline__ void thr_reduce(const double2* __restrict__ npart, double* thrs,
                                           double* ls, double* lq, int t) {
    {
        double s = 0.0, q = 0.0;
#pragma unroll
        for (int i = 0; i < 4; ++i) {
            double2 v = npart[t * 4 + i];
            s += v.x; q += v.y;
        }
        for (int off = 32; off; off >>= 1) {
            s += __shfl_down(s, off, 64);
            q += __shfl_down(q, off, 64);
        }
        if ((t & 63) == 0) { ls[t >> 6] = s; lq[t >> 6] = q; }
    }
    __syncthreads();
    if (t < 2) {
        double sum = ls[2 * t] + ls[2 * t + 1];
        double sq  = lq[2 * t] + lq[2 * t + 1];
        double n = (double)NSP_;
        double mean = sum / n;
        double var = (sq - sum * sum / n) / (n - 1.0);   // ddof=1
        if (var < 0.0) var = 0.0;
        thrs[t] = mean - sqrt(var);
    }
    __syncthreads();
}

__device__ __forceinline__ float dist16(const float* col, const float* nb) {
    float d0 = 0.f, d1 = 0.f, d2 = 0.f, d3 = 0.f;
#pragma unroll
    for (int c = 0; c < 16; c += 4) {
        d0 += fabsf(col[c+0] - nb[c+0]);
        d1 += fabsf(col[c+1] - nb[c+1]);
        d2 += fabsf(col[c+2] - nb[c+2]);
        d3 += fabsf(col[c+3] - nb[c+3]);
    }
    return (d0 + d1) + (d2 + d3);
}

// H/D ring body (templated strides), 256 threads, 8 rings, one parity per block
template<int AS, int FS>
__device__ __forceinline__ void hd_ring(const float* __restrict__ x, float* __restrict__ M,
                                        const double* thrs, float* L, int local, int t) {
    int par = local & 1, wt = (local >> 1) & 7, F = (local >> 4) & 31, b = local >> 9;
    int w0 = wt * 8;
    double thr = thrs[b];
    const float* xb = x + (size_t)b * CDHW_ + (size_t)F * FS + w0;
#pragma unroll
    for (int it = 0; it < 4; ++it) {
        int f = it * 256 + t;                        // 0..1023 float4s
        int c = f >> 5, rem = f & 31, j = rem >> 1, wq = rem & 1;
        float4 v = *(const float4*)(xb + (size_t)c * DHW_ + (size_t)(2 * j + par) * AS + wq * 4);
        int sl = (((c >> 2) ^ (j & 7)) << 2) + (c & 3);
        int rb = (wq * 4) * 512 + j * 32 + sl;
        L[rb] = v.x; L[rb + 512] = v.y; L[rb + 1024] = v.z; L[rb + 1536] = v.w;
    }
    __syncthreads();
    int wl = t & 7, half = (t >> 3) & 1, pos = t >> 4;    // 8 x 2 x 16
    const float* Lr = L + wl * 512;
    int qb = half * 4;
    float col[16], Mv[16], nb[16];
#pragma unroll
    for (int k = 0; k < 4; ++k) {
        float4 cv = *(const float4*)(Lr + pos * 32 + (((qb + k) ^ (pos & 7)) << 2));
        col[4*k] = cv.x; col[4*k+1] = cv.y; col[4*k+2] = cv.z; col[4*k+3] = cv.w;
    }
#pragma unroll
    for (int c = 0; c < 16; ++c) Mv[c] = col[c];
    for (int s = 1; s < 16; ++s) {
        int jj = (pos - s) & 15;
#pragma unroll
        for (int k = 0; k < 4; ++k) {
            float4 nv = *(const float4*)(Lr + jj * 32 + (((qb + k) ^ (jj & 7)) << 2));
            nb[4*k] = nv.x; nb[4*k+1] = nv.y; nb[4*k+2] = nv.z; nb[4*k+3] = nv.w;
        }
        float dh = dist16(col, nb);
        float ds = dh + __shfl_xor(dh, 8, 64);       // combine the two 16-ch halves
        bool cmp;
        bool border = fabs((double)ds - thr) < BORDER;
        if (__ballot(border)) {                      // rare fp64 path
            double d64h = 0.0;
#pragma unroll
            for (int c = 0; c < 16; ++c) d64h += fabs((double)col[c] - (double)nb[c]);
            double other = __shfl_xor(d64h, 8, 64);
            cmp = (d64h + other) < thr;
        } else {
            cmp = (double)ds < thr;
        }
#pragma unroll
        for (int c = 0; c < 16; ++c) Mv[c] = (cmp && nb[c] > Mv[c]) ? nb[c] : Mv[c];
    }
    size_t p = (size_t)F * FS + (size_t)(2 * pos + par) * AS + w0 + wl;
    float* mp = M + ((size_t)b * 65536 + p) * 32 + half * 16;
#pragma unroll
    for (int k = 0; k < 4; ++k) {
        float4 o; o.x = Mv[4*k]; o.y = Mv[4*k+1]; o.z = Mv[4*k+2]; o.w = Mv[4*k+3];
        *(float4*)(mp + 4 * k) = o;
    }
}

// ---------------- unified passes kernel: blk<1024 -> W, <2048 -> H, else D ----------------
__global__ __launch_bounds__(256) void k_passes(const float* __restrict__ x, const double2* __restrict__ npart,
                                                float* __restrict__ Mw, float* __restrict__ Mh,
                                                float* __restrict__ Md) {
    __shared__ __align__(16) float L[4096];          // 16 KB staging
    __shared__ double ls[4], lq[4], thrs[2];
    int t = threadIdx.x;
    thr_reduce(npart, thrs, ls, lq, t);
    int blk = blockIdx.x;
    if (blk < 1024) {
        // ---- W-axis: 4 rings (2 lines x 2 parities); one wave per ring (32 pos x 2 half) ----
#pragma unroll
        for (int it = 0; it < 4; ++it) {
            int f = it * 256 + t;                    // 0..1023 float4s
            int ll = f >> 9;
            int l = blk * 2 + ll;
            int c = (f >> 4) & 31, wq = f & 15;
            const float* lb = x + (size_t)(l >> 10) * CDHW_ + ((l >> 5) & 31) * HW_ + (l & 31) * W_;
            float4 v = *(const float4*)(lb + (size_t)c * DHW_ + wq * 4);
            int cq = c >> 2, cr = c & 3;
            const float* ve = (const float*)&v;
#pragma unroll
            for (int e = 0; e < 4; ++e) {
                int wv2 = wq * 4 + e;
                int p = wv2 >> 1, par = wv2 & 1;
                L[(ll * 2 + par) * 1024 + p * 32 + (((cq ^ (p & 7)) << 2) | cr)] = ve[e];
            }
        }
        __syncthreads();
        int ring = t >> 6, ln = t & 63;
        int pos = ln >> 1, half = ln & 1;
        int ll = ring >> 1, par = ring & 1;
        int l = blk * 2 + ll;
        int b = l >> 10, d = (l >> 5) & 31, h = l & 31;
        double thr = thrs[b];
        const float* Lr = L + ring * 1024;
        int qb = half * 4;
        float col[16], Mv[16], nb[16];
#pragma unroll
        for (int k = 0; k < 4; ++k) {
            float4 cv = *(const float4*)(Lr + pos * 32 + (((qb + k) ^ (pos & 7)) << 2));
            col[4*k] = cv.x; col[4*k+1] = cv.y; col[4*k+2] = cv.z; col[4*k+3] = cv.w;
        }
#pragma unroll
        for (int c = 0; c < 16; ++c) Mv[c] = col[c];
        for (int s = 1; s <= 15; ++s) {              // pairs (s, 32-s)
            int jf = (pos - s) & 31;
#pragma unroll
            for (int k = 0; k < 4; ++k) {
                float4 nv = *(const float4*)(Lr + jf * 32 + (((qb + k) ^ (jf & 7)) << 2));
                nb[4*k] = nv.x; nb[4*k+1] = nv.y; nb[4*k+2] = nv.z; nb[4*k+3] = nv.w;
            }
            float dh = dist16(col, nb);
            float ds = dh + __shfl_xor(dh, 1, 64);   // half partner = ln^1
            bool cmp;
            bool border = fabs((double)ds - thr) < BORDER;
            if (__ballot(border)) {
                double d64h = 0.0;
#pragma unroll
                for (int c = 0; c < 16; ++c) d64h += fabs((double)col[c] - (double)nb[c]);
                double other = __shfl_xor(d64h, 1, 64);
                cmp = (d64h + other) < thr;
            } else {
                cmp = (double)ds < thr;
            }
#pragma unroll
            for (int c = 0; c < 16; ++c) Mv[c] = (cmp && nb[c] > Mv[c]) ? nb[c] : Mv[c];
            int cr2 = __shfl(cmp ? 1 : 0, ((pos + s) & 31) * 2 + half, 64);   // partner's decision
            int jr = (pos + s) & 31;
#pragma unroll
            for (int k = 0; k < 4; ++k) {
                float4 nv = *(const float4*)(Lr + jr * 32 + (((qb + k) ^ (jr & 7)) << 2));
                nb[4*k] = nv.x; nb[4*k+1] = nv.y; nb[4*k+2] = nv.z; nb[4*k+3] = nv.w;
            }
            bool cmpr = (cr2 != 0);
#pragma unroll
            for (int c = 0; c < 16; ++c) Mv[c] = (cmpr && nb[c] > Mv[c]) ? nb[c] : Mv[c];
        }
        {   // s = 16 self-paired
            int jj = (pos + 16) & 31;
#pragma unroll
            for (int k = 0; k < 4; ++k) {
                float4 nv = *(const float4*)(Lr + jj * 32 + (((qb + k) ^ (jj & 7)) << 2));
                nb[4*k] = nv.x; nb[4*k+1] = nv.y; nb[4*k+2] = nv.z; nb[4*k+3] = nv.w;
            }
            float dh = dist16(col, nb);
            float ds = dh + __shfl_xor(dh, 1, 64);
            bool cmp;
            bool border = fabs((double)ds - thr) < BORDER;
            if (__ballot(border)) {
                double d64h = 0.0;
#pragma unroll
                for (int c = 0; c < 16; ++c) d64h += fabs((double)col[c] - (double)nb[c]);
                double other = __shfl_xor(d64h, 1, 64);
                cmp = (d64h + other) < thr;
            } else {
                cmp = (double)ds < thr;
            }
#pragma unroll
            for (int c = 0; c < 16; ++c) Mv[c] = (cmp && nb[c] > Mv[c]) ? nb[c] : Mv[c];
        }
        size_t ppt = (size_t)d * HW_ + h * W_ + 2 * pos + par;
        float* mp = Mw + ((size_t)b * 65536 + ppt) * 32 + half * 16;
#pragma unroll
        for (int k = 0; k < 4; ++k) {
            float4 o; o.x = Mv[4*k]; o.y = Mv[4*k+1]; o.z = Mv[4*k+2]; o.w = Mv[4*k+3];
            *(float4*)(mp + 4 * k) = o;
        }
    } else if (blk < 2048) {
        hd_ring<W_, HW_>(x, Mh, thrs, L, blk - 1024, t);   // H pass (F = d)
    } else {
        hd_ring<HW_, W_>(x, Md, thrs, L, blk - 2048, t);   // D pass (F = h)
    }
}

// ---------------- 1x1x1 conv (64 -> 32); z2 = relu(max3(Mw,Mh,Md) - x) inline ----------------
__global__ __launch_bounds__(256, 4) void k_conv(const float* __restrict__ x,
                                                 const float* __restrict__ Mw, const float* __restrict__ Mh,
                                                 const float* __restrict__ Md,
                                                 const float* __restrict__ w, const float* __restrict__ bias,
                                                 float* __restrict__ y) {
    int t = threadIdx.x;
    int blk = blockIdx.x;                            // 0..2047
    int b = blk >> 10;
    int p0 = (blk & 1023) * 64;
    int og = __builtin_amdgcn_readfirstlane(t >> 6); // wave-uniform -> weights stay scalar
    int pl = t & 63;
    const float* xb = x + (size_t)b * CDHW_ + p0 + pl;
    size_t moff = ((size_t)b * 65536 + p0 + pl) * 32;
    const float4* mw = (const float4*)(Mw + moff);
    const float4* mh = (const float4*)(Mh + moff);
    const float4* md = (const float4*)(Md + moff);
    const float* wo = w + og * 512;                  // SGPR base -> s_load weights
    const float* bo = bias + og * 8;
    float a[8], xv[32];
#pragma unroll
    for (int k = 0; k < 8; ++k) a[k] = bo[k];
#pragma unroll
    for (int c = 0; c < 32; c += 4) {                // x half (L1-reused across the 4 waves)
        xv[c+0] = xb[(size_t)(c+0) * DHW_];
        xv[c+1] = xb[(size_t)(c+1) * DHW_];
        xv[c+2] = xb[(size_t)(c+2) * DHW_];
        xv[c+3] = xb[(size_t)(c+3) * DHW_];
#pragma unroll
        for (int k = 0; k < 8; ++k) {
            a[k] = fmaf(wo[k*64 + c+0], xv[c+0], a[k]);
            a[k] = fmaf(wo[k*64 + c+1], xv[c+1], a[k]);
            a[k] = fmaf(wo[k*64 + c+2], xv[c+2], a[k]);
            a[k] = fmaf(wo[k*64 + c+3], xv[c+3], a[k]);
        }
    }
#pragma unroll
    for (int q = 0; q < 8; ++q) {                    // z2 half (3x contiguous 128B/point + max3)
        float4 vw = mw[q], vh = mh[q], vd = md[q];
        float z0 = fmaxf(fmaxf(fmaxf(vw.x, vh.x), vd.x) - xv[4*q+0], 0.f);
        float z1 = fmaxf(fmaxf(fmaxf(vw.y, vh.y), vd.y) - xv[4*q+1], 0.f);
        float z2 = fmaxf(fmaxf(fmaxf(vw.z, vh.z), vd.z) - xv[4*q+2], 0.f);
        float z3 = fmaxf(fmaxf(fmaxf(vw.w, vh.w), vd.w) - xv[4*q+3], 0.f);
#pragma unroll
        for (int k = 0; k < 8; ++k) {
            a[k] = fmaf(wo[k*64 + 32 + q*4 + 0], z0, a[k]);
            a[k] = fmaf(wo[k*64 + 32 + q*4 + 1], z1, a[k]);
            a[k] = fmaf(wo[k*64 + 32 + q*4 + 2], z2, a[k]);
            a[k] = fmaf(wo[k*64 + 32 + q*4 + 3], z3, a[k]);
        }
    }
    float* yb = y + (size_t)b * CDHW_ + p0 + pl;
#pragma unroll
    for (int k = 0; k < 8; ++k) yb[(size_t)(og * 8 + k) * DHW_] = a[k];
}

// ---------------- BN batch stats from y -> per-block partials ----------------
__global__ __launch_bounds__(256) void k_stats(const float* __restrict__ y, double2* __restrict__ spart) {
    int o = blockIdx.y, ch = blockIdx.x;
    float s = 0.f, q = 0.f;
#pragma unroll
    for (int b = 0; b < 2; ++b) {
        const float4* yp = (const float4*)(y + (size_t)b * CDHW_ + (size_t)o * DHW_ + ch * 4096);
#pragma unroll
        for (int i = 0; i < 4; ++i) {
            float4 v = yp[i * 256 + threadIdx.x];
            s += ((v.x + v.y) + (v.z + v.w));
            q += ((v.x*v.x + v.y*v.y) + (v.z*v.z + v.w*v.w));
        }
    }
    double sd = s, qd = q;
    for (int off = 32; off; off >>= 1) {
        sd += __shfl_down(sd, off, 64);
        qd += __shfl_down(qd, off, 64);
    }
    __shared__ double ls[4], lq[4];
    int wv = threadIdx.x >> 6;
    if ((threadIdx.x & 63) == 0) { ls[wv] = sd; lq[wv] = qd; }
    __syncthreads();
    if (threadIdx.x == 0) {
        double2 out;
        out.x = (ls[0] + ls[1]) + (ls[2] + ls[3]);
        out.y = (lq[0] + lq[1]) + (lq[2] + lq[3]);
        spart[o * 16 + ch] = out;
    }
}

// ---------------- BN normalize + exact GELU, in-place ----------------
__global__ __launch_bounds__(256) void k_out(float* __restrict__ y, const double2* __restrict__ spart,
                                             const float* __restrict__ gamma, const float* __restrict__ beta) {
    int idx = blockIdx.x * 256 + threadIdx.x;       // over 1,048,576 float4
    int o = (blockIdx.x >> 6) & 31;                  // wave-uniform channel
    double sm = 0.0, sq = 0.0;
#pragma unroll
    for (int ch = 0; ch < 16; ++ch) {
        double2 v = spart[o * 16 + ch];
        sm += v.x; sq += v.y;
    }
    double mu = sm / (double)BN_N_;
    double var = sq / (double)BN_N_ - mu * mu;
    float rstd = (float)(1.0 / sqrt(var + 1e-5));
    float mu_f = (float)mu;
    float g = gamma[o], be = beta[o];
    float4 v = ((const float4*)y)[idx];
    float* vv = (float*)&v;
#pragma unroll
    for (int j = 0; j < 4; ++j) {
        float t = (vv[j] - mu_f) * rstd * g + be;
        vv[j] = 0.5f * t * (1.f + erff(t * 0.70710678118654752f));
    }
    ((float4*)y)[idx] = v;
}

extern "C" void kernel_launch(void* const* d_in, const int* in_sizes, int n_in,
                              void* d_out, int out_size, void* d_ws, size_t ws_size,
                              hipStream_t stream) {
    const float* x     = (const float*)d_in[0];
    const float* w     = (const float*)d_in[1];
    const float* bias  = (const float*)d_in[2];
    const float* gamma = (const float*)d_in[3];
    const float* beta  = (const float*)d_in[4];
    float* out = (float*)d_out;
    float* Mw = (float*)d_ws;
    float* Mh = (float*)((char*)d_ws + MH_OFF);
    float* Md = (float*)((char*)d_ws + MD_OFF);
    double2* npart = (double2*)((char*)d_ws + RED_OFF + 256);
    double2* spart = (double2*)((char*)d_ws + RED_OFF + 256 + 16384);

    k_norm  <<<1024, 256, 0, stream>>>(x, npart);
    k_passes<<<3072, 256, 0, stream>>>(x, npart, Mw, Mh, Md);
    k_conv  <<<2048, 256, 0, stream>>>(x, Mw, Mh, Md, w, bias, out);
    k_stats <<<dim3(16, 32), 256, 0, stream>>>(out, spart);
    k_out   <<<4096, 256, 0, stream>>>(out, spart, gamma, beta);
}